// Round 1
// baseline (451.768 us; speedup 1.0000x reference)
//
#include <hip/hip_runtime.h>

// Problem constants (from reference setup_inputs):
//   B=16, C=512, h=w=96 -> HW=9216
//   nodes=7, hidden=256, out_c=512
// KEY INSIGHT: softmax over n of (score_pix[b,p] + score_node[b,n]) is
// shift-invariant in score_pix -> attn depends only on (b,n). Hence
// feat[b,p,o] = relu( sum_n attn[b,n] * (x[b,n,:] . W[:,o]) ) is independent
// of p. res_feature (302 MB) never affects the output. The kernel is a tiny
// (16x512) computation + a 302 MB broadcast write (write-BW bound, ~48 us).

#define NB      16
#define NC      512
#define NHW     9216      // 96*96
#define NODES   7
#define HIDDEN  256
#define OUTC    512

__global__ __launch_bounds__(256) void compute_v_kernel(
    const float* __restrict__ x,        // (B, NODES, HIDDEN) = input[0]
    const float* __restrict__ node_fea, // (C + HIDDEN)
    const float* __restrict__ weight,   // (HIDDEN, OUTC)
    float* __restrict__ v)              // (B, OUTC)  in d_ws
{
    const int b = blockIdx.x;      // 0..15
    const int t = threadIdx.x;     // 0..255

    __shared__ float s_y[HIDDEN];
    __shared__ float s_attn[NODES];
    __shared__ float s_red[4];

    const float* xb = x + (size_t)b * NODES * HIDDEN;
    const float nf = node_fea[NC + t];   // nf_node[t]

    // score_node[n] = sum_h x[b,n,h] * nf_node[h]  (block reduction)
    for (int n = 0; n < NODES; n++) {
        float p = xb[n * HIDDEN + t] * nf;
        #pragma unroll
        for (int off = 32; off >= 1; off >>= 1) p += __shfl_down(p, off, 64);
        if ((t & 63) == 0) s_red[t >> 6] = p;
        __syncthreads();
        if (t == 0) s_attn[n] = s_red[0] + s_red[1] + s_red[2] + s_red[3];
        __syncthreads();
    }

    // softmax over the 7 node scores (thread 0; trivially cheap)
    if (t == 0) {
        float m = s_attn[0];
        #pragma unroll
        for (int n = 1; n < NODES; n++) m = fmaxf(m, s_attn[n]);
        float e[NODES];
        float sum = 0.f;
        #pragma unroll
        for (int n = 0; n < NODES; n++) { e[n] = __expf(s_attn[n] - m); sum += e[n]; }
        float inv = 1.f / sum;
        #pragma unroll
        for (int n = 0; n < NODES; n++) s_attn[n] = e[n] * inv;
    }
    __syncthreads();

    // y[h] = sum_n attn[n] * x[b,n,h]
    float y = 0.f;
    #pragma unroll
    for (int n = 0; n < NODES; n++) y += s_attn[n] * xb[n * HIDDEN + t];
    s_y[t] = y;
    __syncthreads();

    // v[b,o] = relu( sum_h y[h] * W[h,o] ); each thread does o=t and o=t+256.
    float acc0 = 0.f, acc1 = 0.f;
    for (int h = 0; h < HIDDEN; h++) {
        const float yh = s_y[h];                 // LDS broadcast, no conflict
        acc0 += yh * weight[h * OUTC + t];       // coalesced across threads
        acc1 += yh * weight[h * OUTC + t + 256];
    }
    v[b * OUTC + t]       = fmaxf(acc0, 0.f);
    v[b * OUTC + t + 256] = fmaxf(acc1, 0.f);
}

// Broadcast v[b,o] across the 9216 pixels of out[b,o,:,:].
// One block per (b,o) row; 256 threads x 9 float4 stores = 9216 floats.
__global__ __launch_bounds__(256) void broadcast_kernel(
    const float* __restrict__ v, float* __restrict__ out)
{
    const int row = blockIdx.x;             // b*OUTC + o, 0..8191
    const float val = v[row];               // L2-resident after kernel A
    const float4 f4 = make_float4(val, val, val, val);
    float4* o4 = reinterpret_cast<float4*>(out) + (size_t)row * (NHW / 4);
    #pragma unroll
    for (int i = 0; i < 9; i++)
        o4[threadIdx.x + i * 256] = f4;     // fully coalesced 16B stores
}

extern "C" void kernel_launch(void* const* d_in, const int* in_sizes, int n_in,
                              void* d_out, int out_size, void* d_ws, size_t ws_size,
                              hipStream_t stream) {
    const float* x        = (const float*)d_in[0]; // (1,B,NODES,HIDDEN)
    // d_in[1] = res_feature — mathematically irrelevant (softmax shift-invariance)
    const float* node_fea = (const float*)d_in[2]; // (C+HIDDEN, 1)
    const float* weight   = (const float*)d_in[3]; // (HIDDEN, OUTC)
    float* out = (float*)d_out;
    float* v   = (float*)d_ws;                     // 16*512 floats = 32 KB

    compute_v_kernel<<<NB, 256, 0, stream>>>(x, node_fea, weight, v);
    broadcast_kernel<<<NB * OUTC, 256, 0, stream>>>(v, out);
}

// Round 3
// 429.554 us; speedup vs baseline: 1.0517x; 1.0517x over previous
//
#include <hip/hip_runtime.h>

// Problem constants (from reference setup_inputs):
//   B=16, C=512, h=w=96 -> HW=9216, nodes=7, hidden=256, out_c=512
//
// KEY INSIGHT (verified R1, absmax 1.5e-5): softmax over n of
// (score_pix[b,p] + score_node[b,n]) is shift-invariant in score_pix ->
// attn depends only on (b,n) -> feat[b,p,o] is independent of p.
// res_feature (302 MB) never affects the output. Output = relu(v[b,o])
// broadcast over 9216 pixels: a pure 302 MB write problem (~48 us at BW).
//
// R3: single fused kernel (as R2), with the nontemporal store going through
// a native Clang ext_vector_type (HIP float4 is rejected by the builtin).

#define NB      16
#define NC      512
#define NHW     9216      // 96*96
#define NODES   7
#define HIDDEN  256
#define OUTC    512

typedef float v4f __attribute__((ext_vector_type(4)));

__global__ __launch_bounds__(256) void fused_kernel(
    const float* __restrict__ x,        // (B, NODES, HIDDEN)
    const float* __restrict__ node_fea, // (C + HIDDEN)
    const float* __restrict__ weight,   // (HIDDEN, OUTC)
    float* __restrict__ out)            // (B, OUTC, HW)
{
    const int row = blockIdx.x;         // b*OUTC + o
    const int b   = row >> 9;           // /512
    const int o   = row & 511;
    const int t   = threadIdx.x;        // 0..255 == hidden index h
    const int lane = t & 63;
    const int wv   = t >> 6;            // wave id 0..3

    __shared__ float s_part[4][NODES];  // per-wave partial score_node sums
    __shared__ float s_vpart[4];        // per-wave partials for final dot
    __shared__ float s_v;

    const float* xb = x + (size_t)b * NODES * HIDDEN;
    const float nf = node_fea[NC + t];  // nf_node[t]

    // ---- score_node[n] = sum_h x[b,n,h]*nf_node[h], 7 sums at once ----
    float xv[NODES];
    float p[NODES];
    #pragma unroll
    for (int n = 0; n < NODES; n++) {
        xv[n] = xb[n * HIDDEN + t];
        p[n]  = xv[n] * nf;
    }
    #pragma unroll
    for (int off = 32; off >= 1; off >>= 1) {
        #pragma unroll
        for (int n = 0; n < NODES; n++) p[n] += __shfl_down(p[n], off, 64);
    }
    if (lane == 0) {
        #pragma unroll
        for (int n = 0; n < NODES; n++) s_part[wv][n] = p[n];
    }
    __syncthreads();

    // ---- every thread redundantly: totals -> softmax -> y_t ----
    float sc[NODES];
    #pragma unroll
    for (int n = 0; n < NODES; n++)
        sc[n] = s_part[0][n] + s_part[1][n] + s_part[2][n] + s_part[3][n];
    float m = sc[0];
    #pragma unroll
    for (int n = 1; n < NODES; n++) m = fmaxf(m, sc[n]);
    float sum = 0.f;
    #pragma unroll
    for (int n = 0; n < NODES; n++) { sc[n] = __expf(sc[n] - m); sum += sc[n]; }
    const float inv = 1.f / sum;

    float y = 0.f;
    #pragma unroll
    for (int n = 0; n < NODES; n++) y += sc[n] * xv[n];
    y *= inv;                            // y_t = sum_n attn[n]*x[b,n,t]

    // ---- v = relu( sum_h y_h * W[h,o] ): block reduction ----
    float vp = y * weight[t * OUTC + o];
    #pragma unroll
    for (int off = 32; off >= 1; off >>= 1) vp += __shfl_down(vp, off, 64);
    if (lane == 0) s_vpart[wv] = vp;
    __syncthreads();
    if (t == 0)
        s_v = fmaxf(s_vpart[0] + s_vpart[1] + s_vpart[2] + s_vpart[3], 0.f);
    __syncthreads();

    // ---- broadcast: 9216 floats = 256 threads x 9 float4, non-temporal ----
    const float val = s_v;
    const v4f f4 = { val, val, val, val };
    v4f* o4 = reinterpret_cast<v4f*>(out) + (size_t)row * (NHW / 4);
    #pragma unroll
    for (int i = 0; i < 9; i++)
        __builtin_nontemporal_store(f4, &o4[t + i * 256]);
}

extern "C" void kernel_launch(void* const* d_in, const int* in_sizes, int n_in,
                              void* d_out, int out_size, void* d_ws, size_t ws_size,
                              hipStream_t stream) {
    const float* x        = (const float*)d_in[0]; // (1,B,NODES,HIDDEN)
    // d_in[1] = res_feature — mathematically irrelevant (softmax shift-invariance)
    const float* node_fea = (const float*)d_in[2]; // (C+HIDDEN, 1)
    const float* weight   = (const float*)d_in[3]; // (HIDDEN, OUTC)
    float* out = (float*)d_out;

    fused_kernel<<<NB * OUTC, 256, 0, stream>>>(x, node_fea, weight, out);
}